// Round 3
// baseline (316.681 us; speedup 1.0000x reference)
//
#include <hip/hip_runtime.h>

// WeightedBCELoss: out[b][s] = labels==0 ? -log(1-pred) : -weight[b]*log(pred)
// BATCH=4096, SENT=8192, fp32 except labels (int32).
// Memory-bound stream: 384 MB true traffic -> ~61 us floor @ 6.3 TB/s.
// R2: 4x float4 per thread (MLP) + non-temporal stores, using native vector
//     types (__builtin_nontemporal_store rejects HIP_vector_type structs).

#define WBCE_BATCH 4096
#define WBCE_SENT  8192
#define LOG2_VEC_PER_ROW 11   // SENT/4 = 2048 float4 per row
#define VPT 4                 // float4 groups per thread

typedef float nfloat4 __attribute__((ext_vector_type(4)));
typedef int   nint4   __attribute__((ext_vector_type(4)));

__global__ __launch_bounds__(256) void WeightedBCELoss_70128226009669_kernel(
    const nfloat4* __restrict__ pred4,
    const nint4*  __restrict__ lab4,
    const float* __restrict__ weight,
    nfloat4* __restrict__ out4)
{
    // Block b covers vec indices [b*1024, b*1024+1024), thread t takes
    // {base+t, base+256+t, base+512+t, base+768+t} — each chunk coalesced.
    const int base = blockIdx.x * (256 * VPT) + threadIdx.x;

    // 1024 | 2048 => a block never straddles a row; weight is wave-uniform.
    const float w = weight[base >> LOG2_VEC_PER_ROW];

    nfloat4 p[VPT];
    nint4   l[VPT];
#pragma unroll
    for (int j = 0; j < VPT; ++j) {
        p[j] = pred4[base + j * 256];
        l[j] = lab4[base + j * 256];
    }

#pragma unroll
    for (int j = 0; j < VPT; ++j) {
        nfloat4 o;
#pragma unroll
        for (int e = 0; e < 4; ++e) {
            // Pick the log argument first: ONE log per element.
            const float x = (l[j][e] == 0) ? (1.0f - p[j][e]) : p[j][e];
            const float s = (l[j][e] == 0) ? 1.0f : w;
            o[e] = -s * __logf(x);
        }
        // Output is never re-read: non-temporal store avoids L2/L3 write-allocate
        // evicting the restore-warmed inputs.
        __builtin_nontemporal_store(o, &out4[base + j * 256]);
    }
}

extern "C" void kernel_launch(void* const* d_in, const int* in_sizes, int n_in,
                              void* d_out, int out_size, void* d_ws, size_t ws_size,
                              hipStream_t stream) {
    const nfloat4* pred4  = (const nfloat4*)d_in[0];
    const nint4*   lab4   = (const nint4*)d_in[1];
    const float*   weight = (const float*)d_in[2];
    nfloat4* out4 = (nfloat4*)d_out;

    const int n_vec = (WBCE_BATCH * WBCE_SENT) / 4;  // 8,388,608
    const int block = 256;
    const int grid = n_vec / (block * VPT);          // 8192 blocks — exact, no tail

    WeightedBCELoss_70128226009669_kernel<<<grid, block, 0, stream>>>(
        pred4, lab4, weight, out4);
}

// Round 4
// 307.272 us; speedup vs baseline: 1.0306x; 1.0306x over previous
//
#include <hip/hip_runtime.h>

// WeightedBCELoss: out[b][s] = labels==0 ? -log(1-pred) : -weight[b]*log(pred)
// BATCH=4096, SENT=8192, fp32 except labels (int32).
// Mandatory traffic: 384 MB (2R:1W) -> ~72 us floor at triad-mix ceiling (~5.3 TB/s).
// R3: VPT=2 (two independent load pairs in flight, fits VGPR budget without
//     serialization), PLAIN cached stores (R2's nt stores bypassed L2 write
//     coalescing and regressed).

#define WBCE_BATCH 4096
#define WBCE_SENT  8192
#define LOG2_VEC_PER_ROW 11   // SENT/4 = 2048 float4 per row
#define VPT 2                 // float4 groups per thread

typedef float nfloat4 __attribute__((ext_vector_type(4)));
typedef int   nint4   __attribute__((ext_vector_type(4)));

__global__ __launch_bounds__(256) void WeightedBCELoss_70128226009669_kernel(
    const nfloat4* __restrict__ pred4,
    const nint4*  __restrict__ lab4,
    const float* __restrict__ weight,
    nfloat4* __restrict__ out4)
{
    // Block b covers vec indices [b*512, b*512+512); thread t takes
    // {base+t, base+256+t} — each access instruction is perfectly coalesced
    // (1 KB contiguous per wave per load).
    const int base = blockIdx.x * (256 * VPT) + threadIdx.x;

    // 512 | 2048 => a block never straddles a row; weight is wave-uniform.
    const float w = weight[base >> LOG2_VEC_PER_ROW];

    nfloat4 p[VPT];
    nint4   l[VPT];
#pragma unroll
    for (int j = 0; j < VPT; ++j) {
        p[j] = pred4[base + j * 256];
        l[j] = lab4[base + j * 256];
    }

#pragma unroll
    for (int j = 0; j < VPT; ++j) {
        nfloat4 o;
#pragma unroll
        for (int e = 0; e < 4; ++e) {
            // Pick the log argument first: ONE log per element.
            const float x = (l[j][e] == 0) ? (1.0f - p[j][e]) : p[j][e];
            const float s = (l[j][e] == 0) ? 1.0f : w;
            o[e] = -s * __logf(x);
        }
        out4[base + j * 256] = o;   // plain store: keep L2 write coalescing
    }
}

extern "C" void kernel_launch(void* const* d_in, const int* in_sizes, int n_in,
                              void* d_out, int out_size, void* d_ws, size_t ws_size,
                              hipStream_t stream) {
    const nfloat4* pred4  = (const nfloat4*)d_in[0];
    const nint4*   lab4   = (const nint4*)d_in[1];
    const float*   weight = (const float*)d_in[2];
    nfloat4* out4 = (nfloat4*)d_out;

    const int n_vec = (WBCE_BATCH * WBCE_SENT) / 4;  // 8,388,608
    const int block = 256;
    const int grid = n_vec / (block * VPT);          // 16,384 blocks — exact, no tail

    WeightedBCELoss_70128226009669_kernel<<<grid, block, 0, stream>>>(
        pred4, lab4, weight, out4);
}